// Round 10
// baseline (190.194 us; speedup 1.0000x reference)
//
#include <hip/hip_runtime.h>
#include <hip/hip_bf16.h>
#include <math.h>

typedef __bf16 bf16;
typedef unsigned short u16;
typedef __bf16 bf16x8 __attribute__((ext_vector_type(8)));
typedef float  f32x4  __attribute__((ext_vector_type(4)));

#define D_MODEL 1024
#define NHEAD   16
#define HD      64
#define BATCH   2
#define SEQ     2048
#define MTOT    (BATCH*SEQ)   /* 4096 */

// exp(s/8) = exp2(s * 0.125*log2(e)); folded into Q at qkv-write time
#define EXPSCALE 0.18033688011116016f

// async global->LDS, 16B per lane. LDS dest is wave-uniform base + lane*16.
__device__ __forceinline__ void async16(const void* g, void* l) {
    __builtin_amdgcn_global_load_lds(
        (__attribute__((address_space(1))) unsigned int*)g,
        (__attribute__((address_space(3))) unsigned int*)l,
        16, 0, 0);
}

// ---------------------------------------------------------------------------
// f32 -> bf16 cast: z=0 -> x (4M elems), z=1..4 -> Wq,Wk,Wv,Wo (1M each)
// ---------------------------------------------------------------------------
__global__ __launch_bounds__(256) void cast_kernel(
    const float* __restrict__ x,
    const float* __restrict__ wq, const float* __restrict__ wk,
    const float* __restrict__ wv, const float* __restrict__ wo,
    bf16* __restrict__ xb, bf16* __restrict__ wqb, bf16* __restrict__ wkb,
    bf16* __restrict__ wvb, bf16* __restrict__ wob)
{
    const int z = blockIdx.y;
    const float* src;
    bf16* dst;
    int n;
    if (z == 0)      { src = x;  dst = xb;  n = MTOT * D_MODEL; }
    else if (z == 1) { src = wq; dst = wqb; n = D_MODEL * D_MODEL; }
    else if (z == 2) { src = wk; dst = wkb; n = D_MODEL * D_MODEL; }
    else if (z == 3) { src = wv; dst = wvb; n = D_MODEL * D_MODEL; }
    else             { src = wo; dst = wob; n = D_MODEL * D_MODEL; }

    int i = (blockIdx.x * 256 + threadIdx.x) * 8;
    if (i >= n) return;
    float4 a = *(const float4*)(src + i);
    float4 b = *(const float4*)(src + i + 4);
    bf16x8 o;
    o[0] = (bf16)a.x; o[1] = (bf16)a.y; o[2] = (bf16)a.z; o[3] = (bf16)a.w;
    o[4] = (bf16)b.x; o[5] = (bf16)b.y; o[6] = (bf16)b.z; o[7] = (bf16)b.w;
    *(bf16x8*)(dst + i) = o;
}

// ---------------------------------------------------------------------------
// GEMM core 128x128, BK=64 (16 K-iters), single-buffered 2-phase.
// R7 A/B: explicit dbuf = null (implicit wave-level overlap at >=2 blocks/CU
// already covers the load latency; the vmcnt(0) barrier drain is structural
// - m99/m100/m233). 563 TF = 93% of the 2-phase structure's 607 TF ceiling.
// ---------------------------------------------------------------------------
__device__ __forceinline__ void gemm_core(const bf16* __restrict__ A,
                                          const bf16* __restrict__ W,
                                          int m0, int n0,
                                          f32x4 acc[4][4],
                                          u16* lA, u16* lB)
{
    const int tid  = threadIdx.x;
    const int lane = tid & 63;
    const int wave = tid >> 6;
    const int wr   = wave >> 1;
    const int wc   = wave & 1;
    const int fr   = lane & 15;
    const int quad = lane >> 4;

    #pragma unroll
    for (int mi = 0; mi < 4; ++mi)
        #pragma unroll
        for (int ni = 0; ni < 4; ++ni)
            #pragma unroll
            for (int e = 0; e < 4; ++e)
                acc[mi][ni][e] = 0.0f;

    const int row = tid >> 3;                       // slot>>3 for c=0
    const int ca  = ((tid & 7) ^ (row & 7)) * 8;    // row&7 invariant under +32
    const bf16* gA[4];
    const bf16* gB[4];
    u16 *sA[4], *sB[4];
    #pragma unroll
    for (int c = 0; c < 4; ++c) {
        int slot = tid + c * 256;
        int r    = row + c * 32;
        gA[c] = A + (size_t)(m0 + r) * 1024 + ca;
        gB[c] = W + (size_t)(n0 + r) * 1024 + ca;
        sA[c] = lA + (size_t)slot * 8;
        sB[c] = lB + (size_t)slot * 8;
    }

    for (int kt = 0; kt < 1024 / 64; ++kt) {
        __syncthreads();
        #pragma unroll
        for (int c = 0; c < 4; ++c) {
            async16(gA[c] + kt * 64, sA[c]);
            async16(gB[c] + kt * 64, sB[c]);
        }
        __syncthreads();

        #pragma unroll
        for (int ks = 0; ks < 2; ++ks) {
            const int sa = ((ks * 4 + quad) ^ (fr & 7)) * 8;
            bf16x8 af[4], bfm[4];
            #pragma unroll
            for (int mi = 0; mi < 4; ++mi)
                af[mi] = *(const bf16x8*)(lA + (wr * 64 + mi * 16 + fr) * 64 + sa);
            #pragma unroll
            for (int ni = 0; ni < 4; ++ni)
                bfm[ni] = *(const bf16x8*)(lB + (wc * 64 + ni * 16 + fr) * 64 + sa);

            #pragma unroll
            for (int mi = 0; mi < 4; ++mi)
                #pragma unroll
                for (int ni = 0; ni < 4; ++ni)
                    acc[mi][ni] = __builtin_amdgcn_mfma_f32_16x16x32_bf16(
                        af[mi], bfm[ni], acc[mi][ni], 0, 0, 0);
        }
    }
}

// ---------------------------------------------------------------------------
// QKV projection, 128x128 tiles, BK=64 (grid 32x8x3 = 768 blocks).
// z=0 -> Q [B,H,S,hd] (pre-scaled by EXPSCALE), z=1 -> K [B,H,S,hd]
// z=2 -> V^T [B,H,hd,S], operand-swapped (A=Wv, B=x) -> coalesced stores.
// ---------------------------------------------------------------------------
__global__ __launch_bounds__(256) void qkv_kernel(
    const bf16* __restrict__ x,
    const bf16* __restrict__ Wq, const bf16* __restrict__ Wk, const bf16* __restrict__ Wv,
    const float* __restrict__ bq, const float* __restrict__ bk, const float* __restrict__ bv,
    bf16* __restrict__ Q, bf16* __restrict__ K, bf16* __restrict__ Vt)
{
    __shared__ __align__(16) u16 lA[128 * 64];
    __shared__ __align__(16) u16 lB[128 * 64];

    const int z = blockIdx.z;
    int m0, n0;
    const bf16 *mA, *mB;
    const float* bias;
    if (z == 2) {           // swapped: rows = features, cols = tokens
        mA = Wv; mB = x; bias = bv;
        m0 = blockIdx.y * 128;
        n0 = blockIdx.x * 128;
    } else {
        mA = x;  mB = (z == 0) ? Wq : Wk; bias = (z == 0) ? bq : bk;
        m0 = blockIdx.x * 128;
        n0 = blockIdx.y * 128;
    }

    f32x4 acc[4][4];
    gemm_core(mA, mB, m0, n0, acc, lA, lB);

    const int lane = threadIdx.x & 63;
    const int wave = threadIdx.x >> 6;
    const int wr = wave >> 1, wc = wave & 1;
    const int col = lane & 15, quad = lane >> 4;

    if (z == 2) {
        #pragma unroll
        for (int mi = 0; mi < 4; ++mi) {
            #pragma unroll
            for (int ni = 0; ni < 4; ++ni) {
                #pragma unroll
                for (int r = 0; r < 4; ++r) {
                    int f = m0 + wr * 64 + mi * 16 + quad * 4 + r;   // feature
                    int t = n0 + wc * 64 + ni * 16 + col;            // token
                    float v = acc[mi][ni][r] + bias[f];
                    int b = t >> 11, s = t & 2047;
                    int h = f >> 6,  d = f & 63;
                    Vt[((size_t)(b * NHEAD + h) * HD + d) * SEQ + s] = (bf16)v;
                }
            }
        }
    } else {
        const float qs = (z == 0) ? EXPSCALE : 1.0f;
        bf16* o = (z == 0) ? Q : K;
        #pragma unroll
        for (int mi = 0; mi < 4; ++mi) {
            #pragma unroll
            for (int ni = 0; ni < 4; ++ni) {
                #pragma unroll
                for (int r = 0; r < 4; ++r) {
                    int m = m0 + wr * 64 + mi * 16 + quad * 4 + r;
                    int n = n0 + wc * 64 + ni * 16 + col;
                    float v = (acc[mi][ni][r] + bias[n]) * qs;
                    int b = m >> 11, s = m & 2047;
                    int h = n >> 6,  d = n & 63;
                    o[((size_t)(b * NHEAD + h) * SEQ + s) * HD + d] = (bf16)v;
                }
            }
        }
    }
}

// ---------------------------------------------------------------------------
// Flash attention, R14 config (best measured): 4-wave blocks, Q-tile 128,
// KVBLK 128 (16 iters), K-row-permuted staging -> full-rate K=32 PV,
// QK(t)->PV(t-1)->softmax(t) interleave, K/V double-buffered (64 KB LDS,
// 2 blocks/CU), setprio around MFMA cluster. R8 A/B: 8-wave merge regressed.
// Slot->K-row permutation: LDS slot row R holds K-row
// j(R) = (R>>5)*32 + ((R>>2)&3)*8 + ((R>>4)&1)*4 + (R&3), so QK output
// pairs (sc[2c],sc[2c+1]) form the K=32 PV A-frag directly.
// Grid (x=bh=32, y=SEQ/128=16): all blocks of a head on one XCD -> K/V L2.
// ---------------------------------------------------------------------------
__global__ __launch_bounds__(256, 2) void attn_kernel(
    const bf16* __restrict__ Q, const bf16* __restrict__ K,
    const bf16* __restrict__ Vt, bf16* __restrict__ O)
{
    __shared__ __align__(16) u16 lK[2][128 * 64];   // [row j'][64 d]
    __shared__ __align__(16) u16 lV[2][64 * 128];   // [row d][128 j]

    const int tid  = threadIdx.x;
    const int lane = tid & 63;
    const int wave = tid >> 6;
    const int col  = lane & 15;
    const int quad = lane >> 4;
    const int bh   = blockIdx.x;
    const int q0   = blockIdx.y * 128;
    const int NT   = SEQ / 128;                      // 16 tiles

    const bf16* Qh = Q  + (size_t)bh * SEQ * HD;
    const bf16* Kh = K  + (size_t)bh * SEQ * HD;
    const bf16* Vh = Vt + (size_t)bh * HD * SEQ;

    // Q fragments (MFMA B-operand): wave rows q0 + wave*32 + qb*16 + col
    bf16x8 qf[2][2];
    #pragma unroll
    for (int qb = 0; qb < 2; ++qb)
        #pragma unroll
        for (int ks = 0; ks < 2; ++ks)
            qf[qb][ks] = *(const bf16x8*)(
                Qh + (size_t)(q0 + wave * 32 + qb * 16 + col) * HD + ks * 32 + quad * 8);

    f32x4 acc_o[2][4];
    #pragma unroll
    for (int qb = 0; qb < 2; ++qb)
        #pragma unroll
        for (int nd = 0; nd < 4; ++nd)
            #pragma unroll
            for (int e = 0; e < 4; ++e) acc_o[qb][nd][e] = 0.0f;
    float rs[2] = {0.0f, 0.0f};
    const f32x4 zero4 = {0.0f, 0.0f, 0.0f, 0.0f};

    // --- staging addresses -------------------------------------------------
    const int r0  = tid >> 3;                        // 0..31
    const int jp  = (((r0 >> 2) & 3) << 3) | (((r0 >> 4) & 1) << 2) | (r0 & 3);
    const int gk0 = ((tid & 7) ^ (r0 & 7)) * 8;      // swizzled K col (bf16)
    const bf16* gKc[4];
    #pragma unroll
    for (int c = 0; c < 4; ++c)
        gKc[c] = Kh + (size_t)(c * 32 + jp) * HD + gk0;

    const int vr0 = tid >> 4;                        // 0..15
    const int gv0 = ((tid & 15) ^ (vr0 & 7)) * 8;    // swizzled j col (bf16)
    const bf16* gVc[4];
    #pragma unroll
    for (int c = 0; c < 4; ++c)
        gVc[c] = Vh + (size_t)(vr0 + c * 16) * SEQ + gv0;

    const int so = tid * 8;                          // u16 offset of slot tid

    // prologue: stage K(0) into lK[0]
    #pragma unroll
    for (int c = 0; c < 4; ++c)
        async16(gKc[c], lK[0] + so + c * 2048);

    bf16x8 pa0[4], pa1[4];   // K=32 P-frags of tile t-1 (qb=0 / qb=1)

    for (int jt = 0; jt < NT; ++jt) {
        // drains vmcnt(0): K(jt) (staged last iter / prologue) and V(jt-1)
        // complete. Re-staged slots were last read before this barrier.
        __syncthreads();

        if (jt + 1 < NT) {
            u16* kd = lK[(jt + 1) & 1];
            #pragma unroll
            for (int c = 0; c < 4; ++c)
                async16(gKc[c] + (size_t)(jt + 1) * 128 * HD, kd + so + c * 2048);
        }
        {
            u16* vd = lV[jt & 1];
            #pragma unroll
            for (int c = 0; c < 4; ++c)
                async16(gVc[c] + jt * 128, vd + so + c * 2048);
        }

        const u16* K_ = lK[jt & 1];

        __builtin_amdgcn_s_setprio(1);

        // S^T = K Q^T : lane holds Q-row=col; sc[nj][e] = P[col][j] with
        // j = (nj>>1)*32 + quad*8 + (nj&1)*4 + e  (K-row permutation)
        f32x4 sc0[8], sc1[8];
        #pragma unroll
        for (int nj = 0; nj < 8; ++nj) {
            bf16x8 kf0 = *(const bf16x8*)(
                K_ + (nj * 16 + col) * 64 + ((0 + quad) ^ (col & 7)) * 8);
            sc0[nj] = __builtin_amdgcn_mfma_f32_16x16x32_bf16(kf0, qf[0][0], zero4, 0, 0, 0);
            sc1[nj] = __builtin_amdgcn_mfma_f32_16x16x32_bf16(kf0, qf[1][0], zero4, 0, 0, 0);
        }
        #pragma unroll
        for (int nj = 0; nj < 8; ++nj) {
            bf16x8 kf1 = *(const bf16x8*)(
                K_ + (nj * 16 + col) * 64 + ((4 + quad) ^ (col & 7)) * 8);
            sc0[nj] = __builtin_amdgcn_mfma_f32_16x16x32_bf16(kf1, qf[0][1], sc0[nj], 0, 0, 0);
            sc1[nj] = __builtin_amdgcn_mfma_f32_16x16x32_bf16(kf1, qf[1][1], sc1[nj], 0, 0, 0);
        }

        // O += P(t-1) V(t-1): K=32 MFMAs; vb = V^T[d][c*32+quad*8+0..7]
        if (jt > 0) {
            const u16* V_ = lV[(jt - 1) & 1];
            #pragma unroll
            for (int c = 0; c < 4; ++c) {
                #pragma unroll
                for (int nd = 0; nd < 4; ++nd) {
                    int row = nd * 16 + col;
                    int jb  = (c * 4 + quad) ^ (row & 7);
                    bf16x8 vb = *(const bf16x8*)(V_ + row * 128 + jb * 8);
                    acc_o[0][nd] = __builtin_amdgcn_mfma_f32_16x16x32_bf16(
                        pa0[c], vb, acc_o[0][nd], 0, 0, 0);
                    acc_o[1][nd] = __builtin_amdgcn_mfma_f32_16x16x32_bf16(
                        pa1[c], vb, acc_o[1][nd], 0, 0, 0);
                }
            }
        }

        __builtin_amdgcn_s_setprio(0);

        // softmax(t): pa[c] = exp2(sc[2c]) ++ exp2(sc[2c+1]) (K=32 A-frag)
        #pragma unroll
        for (int c = 0; c < 4; ++c) {
            bf16x8 t0, t1;
            #pragma unroll
            for (int e = 0; e < 4; ++e) {
                float a = __builtin_amdgcn_exp2f(sc0[2 * c][e]);
                float b = __builtin_amdgcn_exp2f(sc0[2 * c + 1][e]);
                rs[0] += a + b;
                t0[e]     = (bf16)a;
                t0[4 + e] = (bf16)b;
                float a1 = __builtin_amdgcn_exp2f(sc1[2 * c][e]);
                float b1 = __builtin_amdgcn_exp2f(sc1[2 * c + 1][e]);
                rs[1] += a1 + b1;
                t1[e]     = (bf16)a1;
                t1[4 + e] = (bf16)b1;
            }
            pa0[c] = t0;
            pa1[c] = t1;
        }
    }

    // drain V(NT-1) staging (issued at iter NT-1, not yet waited on)
    __syncthreads();

    // epilogue PV(NT-1)
    {
        const u16* V_ = lV[(NT - 1) & 1];
        #pragma unroll
        for (int c = 0; c < 4; ++c) {
            #pragma unroll
            for (int nd = 0; nd < 4; ++nd) {
                int row = nd * 16 + col;
                int jb  = (c * 4 + quad) ^ (row & 7);
                bf16x8 vb = *(const bf16x8*)(V_ + row * 128 + jb * 8);
                acc_o[0][nd] = __builtin_amdgcn_mfma_f32_16x16x32_bf16(
                    pa0[c], vb, acc_o[0][nd], 0, 0, 0);
                acc_o[1][nd] = __builtin_amdgcn_mfma_f32_16x16x32_bf16(
                    pa1[c], vb, acc_o[1][nd], 0, 0, 0);
            }
        }
    }

    // epilogue: reduce row-sums across quads, broadcast, normalize, write
    const int b = bh >> 4, h = bh & 15;
    #pragma unroll
    for (int qb = 0; qb < 2; ++qb) {
        float v = rs[qb];
        v += __shfl_xor(v, 16);
        v += __shfl_xor(v, 32);
        float inv = 1.0f / v;               // lane holds inv for Q-row `col`
        float invr[4];
        #pragma unroll
        for (int r = 0; r < 4; ++r)
            invr[r] = __shfl(inv, quad * 4 + r);   // inv for row quad*4+r
        #pragma unroll
        for (int nd = 0; nd < 4; ++nd) {
            #pragma unroll
            for (int r = 0; r < 4; ++r) {
                int srow = q0 + wave * 32 + qb * 16 + quad * 4 + r;
                int d    = nd * 16 + col;
                float o  = acc_o[qb][nd][r] * invr[r];
                O[((size_t)(b * SEQ + srow)) * D_MODEL + h * HD + d] = (bf16)o;
            }
        }
    }
}

// ---------------------------------------------------------------------------
// Output projection, R17: 128x128 tiles via the verified gemm_core (was
// 128x64). R9 analysis: oproj's 128x64 tile staged 24KB per K-iter for only
// 16 MFMAs - half qkv's MFMA:staging ratio on the same 2-phase skeleton.
// 128x128 doubles per-block arithmetic intensity; grid (32,8) = 256 blocks
// (1/CU; per-CU-iter chain ~= drain + 32-MFMA compute, no sharing needed).
// out(f32) = ctx @ Wo^T + bo; epilogue = qkv z=0 index math + f32 store.
// ---------------------------------------------------------------------------
__global__ __launch_bounds__(256) void oproj_kernel(
    const bf16* __restrict__ A, const bf16* __restrict__ Wo,
    const float* __restrict__ bo, float* __restrict__ out)
{
    __shared__ __align__(16) u16 lA[128 * 64];
    __shared__ __align__(16) u16 lB[128 * 64];

    const int m0 = blockIdx.x * 128;
    const int n0 = blockIdx.y * 128;

    f32x4 acc[4][4];
    gemm_core(A, Wo, m0, n0, acc, lA, lB);

    const int lane = threadIdx.x & 63;
    const int wave = threadIdx.x >> 6;
    const int wr = wave >> 1, wc = wave & 1;
    const int col = lane & 15, quad = lane >> 4;

    #pragma unroll
    for (int mi = 0; mi < 4; ++mi) {
        #pragma unroll
        for (int ni = 0; ni < 4; ++ni) {
            #pragma unroll
            for (int r = 0; r < 4; ++r) {
                int m = m0 + wr * 64 + mi * 16 + quad * 4 + r;
                int n = n0 + wc * 64 + ni * 16 + col;
                out[(size_t)m * D_MODEL + n] = acc[mi][ni][r] + bo[n];
            }
        }
    }
}

extern "C" void kernel_launch(void* const* d_in, const int* in_sizes, int n_in,
                              void* d_out, int out_size, void* d_ws, size_t ws_size,
                              hipStream_t stream)
{
    const float* x  = (const float*)d_in[0];
    const float* Wq = (const float*)d_in[1];
    const float* bq = (const float*)d_in[2];
    const float* Wk = (const float*)d_in[3];
    const float* bk = (const float*)d_in[4];
    const float* Wv = (const float*)d_in[5];
    const float* bv = (const float*)d_in[6];
    const float* Wo = (const float*)d_in[7];
    const float* bo = (const float*)d_in[8];
    float* out = (float*)d_out;

    char* ws = (char*)d_ws;
    const size_t XSZ = (size_t)MTOT * D_MODEL * sizeof(bf16);     // 8 MB
    const size_t WSZ = (size_t)D_MODEL * D_MODEL * sizeof(bf16);  // 2 MB
    bf16* wqb = (bf16*)(ws);
    bf16* wkb = (bf16*)(ws + WSZ);
    bf16* wvb = (bf16*)(ws + 2 * WSZ);
    bf16* wob = (bf16*)(ws + 3 * WSZ);
    bf16* xb  = (bf16*)(ws + 4 * WSZ);
    bf16* Qb  = (bf16*)(ws + 4 * WSZ + XSZ);
    bf16* Kb  = (bf16*)(ws + 4 * WSZ + 2 * XSZ);
    bf16* Vt  = (bf16*)(ws + 4 * WSZ + 3 * XSZ);
    bf16* At  = (bf16*)(ws + 4 * WSZ + 4 * XSZ);

    cast_kernel<<<dim3((MTOT * D_MODEL) / (256 * 8), 5), 256, 0, stream>>>(
        x, Wq, Wk, Wv, Wo, xb, wqb, wkb, wvb, wob);

    qkv_kernel<<<dim3(32, 8, 3), 256, 0, stream>>>(
        xb, wqb, wkb, wvb, bq, bk, bv, Qb, Kb, Vt);

    attn_kernel<<<dim3(BATCH * NHEAD, SEQ / 128), 256, 0, stream>>>(Qb, Kb, Vt, At);

    oproj_kernel<<<dim3(MTOT / 128, D_MODEL / 128), 256, 0, stream>>>(At, wob, bo, out);
}

// Round 11
// 181.630 us; speedup vs baseline: 1.0472x; 1.0472x over previous
//
#include <hip/hip_runtime.h>
#include <hip/hip_bf16.h>
#include <math.h>

typedef __bf16 bf16;
typedef unsigned short u16;
typedef __bf16 bf16x8 __attribute__((ext_vector_type(8)));
typedef float  f32x4  __attribute__((ext_vector_type(4)));

#define D_MODEL 1024
#define NHEAD   16
#define HD      64
#define BATCH   2
#define SEQ     2048
#define MTOT    (BATCH*SEQ)   /* 4096 */

// exp(s/8) = exp2(s * 0.125*log2(e)); folded into Q at qkv-write time
#define EXPSCALE 0.18033688011116016f

// async global->LDS, 16B per lane. LDS dest is wave-uniform base + lane*16.
__device__ __forceinline__ void async16(const void* g, void* l) {
    __builtin_amdgcn_global_load_lds(
        (__attribute__((address_space(1))) unsigned int*)g,
        (__attribute__((address_space(3))) unsigned int*)l,
        16, 0, 0);
}

// ---------------------------------------------------------------------------
// f32 -> bf16 cast: z=0 -> x (4M elems), z=1..4 -> Wq,Wk,Wv,Wo (1M each)
// ---------------------------------------------------------------------------
__global__ __launch_bounds__(256) void cast_kernel(
    const float* __restrict__ x,
    const float* __restrict__ wq, const float* __restrict__ wk,
    const float* __restrict__ wv, const float* __restrict__ wo,
    bf16* __restrict__ xb, bf16* __restrict__ wqb, bf16* __restrict__ wkb,
    bf16* __restrict__ wvb, bf16* __restrict__ wob)
{
    const int z = blockIdx.y;
    const float* src;
    bf16* dst;
    int n;
    if (z == 0)      { src = x;  dst = xb;  n = MTOT * D_MODEL; }
    else if (z == 1) { src = wq; dst = wqb; n = D_MODEL * D_MODEL; }
    else if (z == 2) { src = wk; dst = wkb; n = D_MODEL * D_MODEL; }
    else if (z == 3) { src = wv; dst = wvb; n = D_MODEL * D_MODEL; }
    else             { src = wo; dst = wob; n = D_MODEL * D_MODEL; }

    int i = (blockIdx.x * 256 + threadIdx.x) * 8;
    if (i >= n) return;
    float4 a = *(const float4*)(src + i);
    float4 b = *(const float4*)(src + i + 4);
    bf16x8 o;
    o[0] = (bf16)a.x; o[1] = (bf16)a.y; o[2] = (bf16)a.z; o[3] = (bf16)a.w;
    o[4] = (bf16)b.x; o[5] = (bf16)b.y; o[6] = (bf16)b.z; o[7] = (bf16)b.w;
    *(bf16x8*)(dst + i) = o;
}

// ---------------------------------------------------------------------------
// GEMM core 128x128, BK=64 (16 K-iters), single-buffered 2-phase.
// R7 A/B: explicit dbuf = null (implicit wave-level overlap at >=2 blocks/CU
// already covers the load latency; the vmcnt(0) barrier drain is structural
// - m99/m100/m233). 563 TF = 93% of the 2-phase structure's 607 TF ceiling.
// Session law (R8/R17): on this skeleton, blocks/CU >= 2 beats any
// per-block arithmetic-intensity gain.
// ---------------------------------------------------------------------------
__device__ __forceinline__ void gemm_core(const bf16* __restrict__ A,
                                          const bf16* __restrict__ W,
                                          int m0, int n0,
                                          f32x4 acc[4][4],
                                          u16* lA, u16* lB)
{
    const int tid  = threadIdx.x;
    const int lane = tid & 63;
    const int wave = tid >> 6;
    const int wr   = wave >> 1;
    const int wc   = wave & 1;
    const int fr   = lane & 15;
    const int quad = lane >> 4;

    #pragma unroll
    for (int mi = 0; mi < 4; ++mi)
        #pragma unroll
        for (int ni = 0; ni < 4; ++ni)
            #pragma unroll
            for (int e = 0; e < 4; ++e)
                acc[mi][ni][e] = 0.0f;

    const int row = tid >> 3;                       // slot>>3 for c=0
    const int ca  = ((tid & 7) ^ (row & 7)) * 8;    // row&7 invariant under +32
    const bf16* gA[4];
    const bf16* gB[4];
    u16 *sA[4], *sB[4];
    #pragma unroll
    for (int c = 0; c < 4; ++c) {
        int slot = tid + c * 256;
        int r    = row + c * 32;
        gA[c] = A + (size_t)(m0 + r) * 1024 + ca;
        gB[c] = W + (size_t)(n0 + r) * 1024 + ca;
        sA[c] = lA + (size_t)slot * 8;
        sB[c] = lB + (size_t)slot * 8;
    }

    for (int kt = 0; kt < 1024 / 64; ++kt) {
        __syncthreads();
        #pragma unroll
        for (int c = 0; c < 4; ++c) {
            async16(gA[c] + kt * 64, sA[c]);
            async16(gB[c] + kt * 64, sB[c]);
        }
        __syncthreads();

        #pragma unroll
        for (int ks = 0; ks < 2; ++ks) {
            const int sa = ((ks * 4 + quad) ^ (fr & 7)) * 8;
            bf16x8 af[4], bfm[4];
            #pragma unroll
            for (int mi = 0; mi < 4; ++mi)
                af[mi] = *(const bf16x8*)(lA + (wr * 64 + mi * 16 + fr) * 64 + sa);
            #pragma unroll
            for (int ni = 0; ni < 4; ++ni)
                bfm[ni] = *(const bf16x8*)(lB + (wc * 64 + ni * 16 + fr) * 64 + sa);

            #pragma unroll
            for (int mi = 0; mi < 4; ++mi)
                #pragma unroll
                for (int ni = 0; ni < 4; ++ni)
                    acc[mi][ni] = __builtin_amdgcn_mfma_f32_16x16x32_bf16(
                        af[mi], bfm[ni], acc[mi][ni], 0, 0, 0);
        }
    }
}

// ---------------------------------------------------------------------------
// QKV projection, 128x128 tiles, BK=64 (grid 32x8x3 = 768 blocks, 3/CU).
// z=0 -> Q [B,H,S,hd] (pre-scaled by EXPSCALE), z=1 -> K [B,H,S,hd]
// z=2 -> V^T [B,H,hd,S], operand-swapped (A=Wv, B=x) -> coalesced stores.
// ---------------------------------------------------------------------------
__global__ __launch_bounds__(256) void qkv_kernel(
    const bf16* __restrict__ x,
    const bf16* __restrict__ Wq, const bf16* __restrict__ Wk, const bf16* __restrict__ Wv,
    const float* __restrict__ bq, const float* __restrict__ bk, const float* __restrict__ bv,
    bf16* __restrict__ Q, bf16* __restrict__ K, bf16* __restrict__ Vt)
{
    __shared__ __align__(16) u16 lA[128 * 64];
    __shared__ __align__(16) u16 lB[128 * 64];

    const int z = blockIdx.z;
    int m0, n0;
    const bf16 *mA, *mB;
    const float* bias;
    if (z == 2) {           // swapped: rows = features, cols = tokens
        mA = Wv; mB = x; bias = bv;
        m0 = blockIdx.y * 128;
        n0 = blockIdx.x * 128;
    } else {
        mA = x;  mB = (z == 0) ? Wq : Wk; bias = (z == 0) ? bq : bk;
        m0 = blockIdx.x * 128;
        n0 = blockIdx.y * 128;
    }

    f32x4 acc[4][4];
    gemm_core(mA, mB, m0, n0, acc, lA, lB);

    const int lane = threadIdx.x & 63;
    const int wave = threadIdx.x >> 6;
    const int wr = wave >> 1, wc = wave & 1;
    const int col = lane & 15, quad = lane >> 4;

    if (z == 2) {
        #pragma unroll
        for (int mi = 0; mi < 4; ++mi) {
            #pragma unroll
            for (int ni = 0; ni < 4; ++ni) {
                #pragma unroll
                for (int r = 0; r < 4; ++r) {
                    int f = m0 + wr * 64 + mi * 16 + quad * 4 + r;   // feature
                    int t = n0 + wc * 64 + ni * 16 + col;            // token
                    float v = acc[mi][ni][r] + bias[f];
                    int b = t >> 11, s = t & 2047;
                    int h = f >> 6,  d = f & 63;
                    Vt[((size_t)(b * NHEAD + h) * HD + d) * SEQ + s] = (bf16)v;
                }
            }
        }
    } else {
        const float qs = (z == 0) ? EXPSCALE : 1.0f;
        bf16* o = (z == 0) ? Q : K;
        #pragma unroll
        for (int mi = 0; mi < 4; ++mi) {
            #pragma unroll
            for (int ni = 0; ni < 4; ++ni) {
                #pragma unroll
                for (int r = 0; r < 4; ++r) {
                    int m = m0 + wr * 64 + mi * 16 + quad * 4 + r;
                    int n = n0 + wc * 64 + ni * 16 + col;
                    float v = (acc[mi][ni][r] + bias[n]) * qs;
                    int b = m >> 11, s = m & 2047;
                    int h = n >> 6,  d = n & 63;
                    o[((size_t)(b * NHEAD + h) * SEQ + s) * HD + d] = (bf16)v;
                }
            }
        }
    }
}

// ---------------------------------------------------------------------------
// Flash attention, R14 config (best measured): 4-wave blocks, Q-tile 128,
// KVBLK 128 (16 iters), K-row-permuted staging -> full-rate K=32 PV,
// QK(t)->PV(t-1)->softmax(t) interleave, K/V double-buffered (64 KB LDS,
// 2 blocks/CU), setprio around MFMA cluster. R8 A/B: 8-wave merge regressed.
// Slot->K-row permutation: LDS slot row R holds K-row
// j(R) = (R>>5)*32 + ((R>>2)&3)*8 + ((R>>4)&1)*4 + (R&3), so QK output
// pairs (sc[2c],sc[2c+1]) form the K=32 PV A-frag directly.
// Grid (x=bh=32, y=SEQ/128=16): all blocks of a head on one XCD -> K/V L2.
// ---------------------------------------------------------------------------
__global__ __launch_bounds__(256, 2) void attn_kernel(
    const bf16* __restrict__ Q, const bf16* __restrict__ K,
    const bf16* __restrict__ Vt, bf16* __restrict__ O)
{
    __shared__ __align__(16) u16 lK[2][128 * 64];   // [row j'][64 d]
    __shared__ __align__(16) u16 lV[2][64 * 128];   // [row d][128 j]

    const int tid  = threadIdx.x;
    const int lane = tid & 63;
    const int wave = tid >> 6;
    const int col  = lane & 15;
    const int quad = lane >> 4;
    const int bh   = blockIdx.x;
    const int q0   = blockIdx.y * 128;
    const int NT   = SEQ / 128;                      // 16 tiles

    const bf16* Qh = Q  + (size_t)bh * SEQ * HD;
    const bf16* Kh = K  + (size_t)bh * SEQ * HD;
    const bf16* Vh = Vt + (size_t)bh * HD * SEQ;

    // Q fragments (MFMA B-operand): wave rows q0 + wave*32 + qb*16 + col
    bf16x8 qf[2][2];
    #pragma unroll
    for (int qb = 0; qb < 2; ++qb)
        #pragma unroll
        for (int ks = 0; ks < 2; ++ks)
            qf[qb][ks] = *(const bf16x8*)(
                Qh + (size_t)(q0 + wave * 32 + qb * 16 + col) * HD + ks * 32 + quad * 8);

    f32x4 acc_o[2][4];
    #pragma unroll
    for (int qb = 0; qb < 2; ++qb)
        #pragma unroll
        for (int nd = 0; nd < 4; ++nd)
            #pragma unroll
            for (int e = 0; e < 4; ++e) acc_o[qb][nd][e] = 0.0f;
    float rs[2] = {0.0f, 0.0f};
    const f32x4 zero4 = {0.0f, 0.0f, 0.0f, 0.0f};

    // --- staging addresses -------------------------------------------------
    const int r0  = tid >> 3;                        // 0..31
    const int jp  = (((r0 >> 2) & 3) << 3) | (((r0 >> 4) & 1) << 2) | (r0 & 3);
    const int gk0 = ((tid & 7) ^ (r0 & 7)) * 8;      // swizzled K col (bf16)
    const bf16* gKc[4];
    #pragma unroll
    for (int c = 0; c < 4; ++c)
        gKc[c] = Kh + (size_t)(c * 32 + jp) * HD + gk0;

    const int vr0 = tid >> 4;                        // 0..15
    const int gv0 = ((tid & 15) ^ (vr0 & 7)) * 8;    // swizzled j col (bf16)
    const bf16* gVc[4];
    #pragma unroll
    for (int c = 0; c < 4; ++c)
        gVc[c] = Vh + (size_t)(vr0 + c * 16) * SEQ + gv0;

    const int so = tid * 8;                          // u16 offset of slot tid

    // prologue: stage K(0) into lK[0]
    #pragma unroll
    for (int c = 0; c < 4; ++c)
        async16(gKc[c], lK[0] + so + c * 2048);

    bf16x8 pa0[4], pa1[4];   // K=32 P-frags of tile t-1 (qb=0 / qb=1)

    for (int jt = 0; jt < NT; ++jt) {
        // drains vmcnt(0): K(jt) (staged last iter / prologue) and V(jt-1)
        // complete. Re-staged slots were last read before this barrier.
        __syncthreads();

        if (jt + 1 < NT) {
            u16* kd = lK[(jt + 1) & 1];
            #pragma unroll
            for (int c = 0; c < 4; ++c)
                async16(gKc[c] + (size_t)(jt + 1) * 128 * HD, kd + so + c * 2048);
        }
        {
            u16* vd = lV[jt & 1];
            #pragma unroll
            for (int c = 0; c < 4; ++c)
                async16(gVc[c] + jt * 128, vd + so + c * 2048);
        }

        const u16* K_ = lK[jt & 1];

        __builtin_amdgcn_s_setprio(1);

        // S^T = K Q^T : lane holds Q-row=col; sc[nj][e] = P[col][j] with
        // j = (nj>>1)*32 + quad*8 + (nj&1)*4 + e  (K-row permutation)
        f32x4 sc0[8], sc1[8];
        #pragma unroll
        for (int nj = 0; nj < 8; ++nj) {
            bf16x8 kf0 = *(const bf16x8*)(
                K_ + (nj * 16 + col) * 64 + ((0 + quad) ^ (col & 7)) * 8);
            sc0[nj] = __builtin_amdgcn_mfma_f32_16x16x32_bf16(kf0, qf[0][0], zero4, 0, 0, 0);
            sc1[nj] = __builtin_amdgcn_mfma_f32_16x16x32_bf16(kf0, qf[1][0], zero4, 0, 0, 0);
        }
        #pragma unroll
        for (int nj = 0; nj < 8; ++nj) {
            bf16x8 kf1 = *(const bf16x8*)(
                K_ + (nj * 16 + col) * 64 + ((4 + quad) ^ (col & 7)) * 8);
            sc0[nj] = __builtin_amdgcn_mfma_f32_16x16x32_bf16(kf1, qf[0][1], sc0[nj], 0, 0, 0);
            sc1[nj] = __builtin_amdgcn_mfma_f32_16x16x32_bf16(kf1, qf[1][1], sc1[nj], 0, 0, 0);
        }

        // O += P(t-1) V(t-1): K=32 MFMAs; vb = V^T[d][c*32+quad*8+0..7]
        if (jt > 0) {
            const u16* V_ = lV[(jt - 1) & 1];
            #pragma unroll
            for (int c = 0; c < 4; ++c) {
                #pragma unroll
                for (int nd = 0; nd < 4; ++nd) {
                    int row = nd * 16 + col;
                    int jb  = (c * 4 + quad) ^ (row & 7);
                    bf16x8 vb = *(const bf16x8*)(V_ + row * 128 + jb * 8);
                    acc_o[0][nd] = __builtin_amdgcn_mfma_f32_16x16x32_bf16(
                        pa0[c], vb, acc_o[0][nd], 0, 0, 0);
                    acc_o[1][nd] = __builtin_amdgcn_mfma_f32_16x16x32_bf16(
                        pa1[c], vb, acc_o[1][nd], 0, 0, 0);
                }
            }
        }

        __builtin_amdgcn_s_setprio(0);

        // softmax(t): pa[c] = exp2(sc[2c]) ++ exp2(sc[2c+1]) (K=32 A-frag)
        #pragma unroll
        for (int c = 0; c < 4; ++c) {
            bf16x8 t0, t1;
            #pragma unroll
            for (int e = 0; e < 4; ++e) {
                float a = __builtin_amdgcn_exp2f(sc0[2 * c][e]);
                float b = __builtin_amdgcn_exp2f(sc0[2 * c + 1][e]);
                rs[0] += a + b;
                t0[e]     = (bf16)a;
                t0[4 + e] = (bf16)b;
                float a1 = __builtin_amdgcn_exp2f(sc1[2 * c][e]);
                float b1 = __builtin_amdgcn_exp2f(sc1[2 * c + 1][e]);
                rs[1] += a1 + b1;
                t1[e]     = (bf16)a1;
                t1[4 + e] = (bf16)b1;
            }
            pa0[c] = t0;
            pa1[c] = t1;
        }
    }

    // drain V(NT-1) staging (issued at iter NT-1, not yet waited on)
    __syncthreads();

    // epilogue PV(NT-1)
    {
        const u16* V_ = lV[(NT - 1) & 1];
        #pragma unroll
        for (int c = 0; c < 4; ++c) {
            #pragma unroll
            for (int nd = 0; nd < 4; ++nd) {
                int row = nd * 16 + col;
                int jb  = (c * 4 + quad) ^ (row & 7);
                bf16x8 vb = *(const bf16x8*)(V_ + row * 128 + jb * 8);
                acc_o[0][nd] = __builtin_amdgcn_mfma_f32_16x16x32_bf16(
                    pa0[c], vb, acc_o[0][nd], 0, 0, 0);
                acc_o[1][nd] = __builtin_amdgcn_mfma_f32_16x16x32_bf16(
                    pa1[c], vb, acc_o[1][nd], 0, 0, 0);
            }
        }
    }

    // epilogue: reduce row-sums across quads, broadcast, normalize, write
    const int b = bh >> 4, h = bh & 15;
    #pragma unroll
    for (int qb = 0; qb < 2; ++qb) {
        float v = rs[qb];
        v += __shfl_xor(v, 16);
        v += __shfl_xor(v, 32);
        float inv = 1.0f / v;               // lane holds inv for Q-row `col`
        float invr[4];
        #pragma unroll
        for (int r = 0; r < 4; ++r)
            invr[r] = __shfl(inv, quad * 4 + r);   // inv for row quad*4+r
        #pragma unroll
        for (int nd = 0; nd < 4; ++nd) {
            #pragma unroll
            for (int r = 0; r < 4; ++r) {
                int srow = q0 + wave * 32 + qb * 16 + quad * 4 + r;
                int d    = nd * 16 + col;
                float o  = acc_o[qb][nd][r] * invr[r];
                O[((size_t)(b * SEQ + srow)) * D_MODEL + h * HD + d] = (bf16)o;
            }
        }
    }
}

// ---------------------------------------------------------------------------
// Output projection: 128x64 tiles, BK=64 (512 blocks = 2/CU, 16 K-iters),
// out(f32) = ctx @ Wo^T + bo. R17 A/B: 128x128 retile (256 blocks = 1/CU)
// regressed -6us - cross-block TLP on the 2-phase skeleton is worth more
// than the doubled per-block arithmetic intensity.
// ---------------------------------------------------------------------------
__global__ __launch_bounds__(256) void oproj_kernel(
    const bf16* __restrict__ A, const bf16* __restrict__ Wo,
    const float* __restrict__ bo, float* __restrict__ out)
{
    __shared__ __align__(16) u16 lA[128 * 64];
    __shared__ __align__(16) u16 lB[64 * 64];

    const int m0 = blockIdx.x * 128;
    const int n0 = blockIdx.y * 64;

    const int tid  = threadIdx.x;
    const int lane = tid & 63;
    const int wave = tid >> 6;
    const int wr   = wave >> 1;
    const int wc   = wave & 1;
    const int fr   = lane & 15;
    const int quad = lane >> 4;

    f32x4 acc[4][2];
    #pragma unroll
    for (int mi = 0; mi < 4; ++mi)
        #pragma unroll
        for (int ni = 0; ni < 2; ++ni)
            #pragma unroll
            for (int e = 0; e < 4; ++e)
                acc[mi][ni][e] = 0.0f;

    const int row = tid >> 3;
    const int ca  = ((tid & 7) ^ (row & 7)) * 8;
    const bf16* gA[4];
    u16* sA[4];
    #pragma unroll
    for (int c = 0; c < 4; ++c) {
        int slot = tid + c * 256;
        gA[c] = A + (size_t)(m0 + row + c * 32) * 1024 + ca;
        sA[c] = lA + (size_t)slot * 8;
    }
    const bf16* gB[2];
    u16* sB[2];
    #pragma unroll
    for (int c = 0; c < 2; ++c) {
        int slot = tid + c * 256;
        gB[c] = Wo + (size_t)(n0 + row + c * 32) * 1024 + ca;
        sB[c] = lB + (size_t)slot * 8;
    }

    for (int kt = 0; kt < 1024 / 64; ++kt) {
        __syncthreads();
        #pragma unroll
        for (int c = 0; c < 4; ++c) async16(gA[c] + kt * 64, sA[c]);
        #pragma unroll
        for (int c = 0; c < 2; ++c) async16(gB[c] + kt * 64, sB[c]);
        __syncthreads();

        #pragma unroll
        for (int ks = 0; ks < 2; ++ks) {
            const int sa = ((ks * 4 + quad) ^ (fr & 7)) * 8;
            bf16x8 af[4], bfm[2];
            #pragma unroll
            for (int mi = 0; mi < 4; ++mi)
                af[mi] = *(const bf16x8*)(lA + (wr * 64 + mi * 16 + fr) * 64 + sa);
            #pragma unroll
            for (int ni = 0; ni < 2; ++ni)
                bfm[ni] = *(const bf16x8*)(lB + (wc * 32 + ni * 16 + fr) * 64 + sa);

            #pragma unroll
            for (int mi = 0; mi < 4; ++mi)
                #pragma unroll
                for (int ni = 0; ni < 2; ++ni)
                    acc[mi][ni] = __builtin_amdgcn_mfma_f32_16x16x32_bf16(
                        af[mi], bfm[ni], acc[mi][ni], 0, 0, 0);
        }
    }

    const int col = fr;
    #pragma unroll
    for (int mi = 0; mi < 4; ++mi) {
        #pragma unroll
        for (int ni = 0; ni < 2; ++ni) {
            #pragma unroll
            for (int r = 0; r < 4; ++r) {
                int m = m0 + wr * 64 + mi * 16 + quad * 4 + r;
                int n = n0 + wc * 32 + ni * 16 + col;
                out[(size_t)m * D_MODEL + n] = acc[mi][ni][r] + bo[n];
            }
        }
    }
}

extern "C" void kernel_launch(void* const* d_in, const int* in_sizes, int n_in,
                              void* d_out, int out_size, void* d_ws, size_t ws_size,
                              hipStream_t stream)
{
    const float* x  = (const float*)d_in[0];
    const float* Wq = (const float*)d_in[1];
    const float* bq = (const float*)d_in[2];
    const float* Wk = (const float*)d_in[3];
    const float* bk = (const float*)d_in[4];
    const float* Wv = (const float*)d_in[5];
    const float* bv = (const float*)d_in[6];
    const float* Wo = (const float*)d_in[7];
    const float* bo = (const float*)d_in[8];
    float* out = (float*)d_out;

    char* ws = (char*)d_ws;
    const size_t XSZ = (size_t)MTOT * D_MODEL * sizeof(bf16);     // 8 MB
    const size_t WSZ = (size_t)D_MODEL * D_MODEL * sizeof(bf16);  // 2 MB
    bf16* wqb = (bf16*)(ws);
    bf16* wkb = (bf16*)(ws + WSZ);
    bf16* wvb = (bf16*)(ws + 2 * WSZ);
    bf16* wob = (bf16*)(ws + 3 * WSZ);
    bf16* xb  = (bf16*)(ws + 4 * WSZ);
    bf16* Qb  = (bf16*)(ws + 4 * WSZ + XSZ);
    bf16* Kb  = (bf16*)(ws + 4 * WSZ + 2 * XSZ);
    bf16* Vt  = (bf16*)(ws + 4 * WSZ + 3 * XSZ);
    bf16* At  = (bf16*)(ws + 4 * WSZ + 4 * XSZ);

    cast_kernel<<<dim3((MTOT * D_MODEL) / (256 * 8), 5), 256, 0, stream>>>(
        x, Wq, Wk, Wv, Wo, xb, wqb, wkb, wvb, wob);

    qkv_kernel<<<dim3(32, 8, 3), 256, 0, stream>>>(
        xb, wqb, wkb, wvb, bq, bk, bv, Qb, Kb, Vt);

    attn_kernel<<<dim3(BATCH * NHEAD, SEQ / 128), 256, 0, stream>>>(Qb, Kb, Vt, At);

    oproj_kernel<<<dim3(MTOT / 128, D_MODEL / 64), 256, 0, stream>>>(At, wob, bo, out);
}